// Round 1
// 107.615 us; speedup vs baseline: 1.0234x; 1.0234x over previous
//
#include <hip/hip_runtime.h>
#include <math.h>

// GaussianMixture log-likelihood: ll[n] = logsumexp_m( wlog[m] - dx^T G_m dx )
// arg(n,m) = c0 + c1*x0^2 + c2*x0 + c3*x1^2 + c4*x1 + c5*x0*x1  (log2-scaled)
// R7: R6 structure, fast path widened to CHF=32 with fully packed state:
//  - v2f running max/sum, rescale folded into one v_pk_fma (s = s*resc + cs)
//  - exp2 results accumulated via v2f adds (v_pk_add_f32) instead of 4 scalar adds
//  - complete packed max tree over all 32 elems (R5 lesson: partial coverage
//    -> exp2 overflow -> inf*0 NaN in combine)
// readfirstlane on wave id keeps coefficient loads scalar (R3 lesson).

#if __has_builtin(__builtin_amdgcn_exp2f)
#define EXP2(x) __builtin_amdgcn_exp2f(x)
#else
#define EXP2(x) exp2f(x)
#endif

typedef float v2f __attribute__((ext_vector_type(2)));

#if __has_builtin(__builtin_elementwise_max)
#define PKMAX(a, b) __builtin_elementwise_max(a, b)
#else
static __device__ inline v2f PKMAX(v2f a, v2f b) {
  v2f r; r.x = fmaxf(a.x, b.x); r.y = fmaxf(a.y, b.y); return r;
}
#endif

#define SPLIT 8
#define CHF 32   // fast-path chunk
#define CH 16    // general-path chunk (unchanged from R6)

__global__ __launch_bounds__(256) void prep_kernel(
    const float* __restrict__ mu,
    const float* __restrict__ A,
    const float* __restrict__ w,
    float* __restrict__ C,   // [6][M] planes + header {flag, cb1, cb3, cb5}
    int M) {
  __shared__ float red[256];
  __shared__ int uni[256];
  const int t = threadIdx.x;

  float mx = -INFINITY;
  for (int m = t; m < M; m += 256) mx = fmaxf(mx, w[m]);
  red[t] = mx; __syncthreads();
  for (int s = 128; s > 0; s >>= 1) {
    if (t < s) red[t] = fmaxf(red[t], red[t + s]);
    __syncthreads();
  }
  const float wmax = red[0]; __syncthreads();

  float sum = 0.f;
  for (int m = t; m < M; m += 256) sum += expf(w[m] - wmax);
  red[t] = sum; __syncthreads();
  for (int s = 128; s > 0; s >>= 1) {
    if (t < s) red[t] += red[t + s];
    __syncthreads();
  }
  const float logZ = wmax + logf(red[0]);

  const float r00 = A[0], r01 = A[1], r10 = A[2], r11 = A[3];
  const float rg00 = 0.5f * (r00 * r00 + r01 * r01);
  const float rg01 = 0.5f * (r00 * r10 + r01 * r11);
  const float rg11 = 0.5f * (r10 * r10 + r11 * r11);

  const float LOG2E = 1.44269504088896340736f;
  int myuni = 1;
  for (int m = t; m < M; m += 256) {
    const float a00 = A[m * 4 + 0], a01 = A[m * 4 + 1];
    const float a10 = A[m * 4 + 2], a11 = A[m * 4 + 3];
    const float g00 = 0.5f * (a00 * a00 + a01 * a01);
    const float g01 = 0.5f * (a00 * a10 + a01 * a11);
    const float g11 = 0.5f * (a10 * a10 + a11 * a11);
    const float g01s = 2.0f * g01;
    const float det = g00 * g11 - g01 * g01;
    const float wlog = (w[m] - logZ) + 0.5f * logf(det);
    const float mu0 = mu[m * 2 + 0], mu1 = mu[m * 2 + 1];
    const float c0 = wlog - (g00 * mu0 * mu0 + g01s * mu0 * mu1 + g11 * mu1 * mu1);
    const float c2 = 2.0f * g00 * mu0 + g01s * mu1;
    const float c4 = 2.0f * g11 * mu1 + g01s * mu0;
    C[0 * M + m] = LOG2E * c0;
    C[1 * M + m] = LOG2E * -g00;
    C[2 * M + m] = LOG2E * c2;
    C[3 * M + m] = LOG2E * -g11;
    C[4 * M + m] = LOG2E * c4;
    C[5 * M + m] = LOG2E * -g01s;
    myuni &= (g00 == rg00) & (g01 == rg01) & (g11 == rg11);
  }
  uni[t] = myuni; __syncthreads();
  for (int s = 128; s > 0; s >>= 1) {
    if (t < s) uni[t] &= uni[t + s];
    __syncthreads();
  }
  if (t == 0) {
    ((int*)C)[6 * M + 0] = uni[0];
    C[6 * M + 1] = LOG2E * -rg00;        // cb1
    C[6 * M + 2] = LOG2E * -rg11;        // cb3
    C[6 * M + 3] = LOG2E * -2.0f * rg01; // cb5
  }
}

// One block = 512 threads = 8 waves; all waves cover the SAME 128 samples
// (lane l -> samples blk*128+l and +64), wave v covers comps [v*M/8,(v+1)*M/8).
__global__ __launch_bounds__(512, 4) void gmix_kernel(
    const float* __restrict__ sample,
    const float* __restrict__ C,
    float* __restrict__ out,
    int N, int M) {
  __shared__ float Lmx[SPLIT][2][64];
  __shared__ float Lsm[SPLIT][2][64];

  const int lane = threadIdx.x & 63;
  const int wave = __builtin_amdgcn_readfirstlane((int)(threadIdx.x >> 6));
  const int nA = blockIdx.x * 128 + lane;
  const int nB = nA + 64;

  const float2 xA = (nA < N) ? ((const float2*)sample)[nA] : make_float2(0.f, 0.f);
  const float2 xB = (nB < N) ? ((const float2*)sample)[nB] : make_float2(0.f, 0.f);
  const v2f x0p = {xA.x, xB.x};   // lo = sample A, hi = sample B
  const v2f x1p = {xA.y, xB.y};

  const int flag = ((const int*)C)[6 * M + 0];
  const float cb1 = C[6 * M + 1];
  const float cb3 = C[6 * M + 2];
  const float cb5 = C[6 * M + 3];

  const int Mq = M / SPLIT;
  const int m0 = wave * Mq;                      // SGPR -> scalar loads
  const float* __restrict__ C0 = C + m0;
  const float* __restrict__ C1 = C + M + m0;
  const float* __restrict__ C2 = C + 2 * M + m0;
  const float* __restrict__ C3 = C + 3 * M + m0;
  const float* __restrict__ C4 = C + 4 * M + m0;
  const float* __restrict__ C5 = C + 5 * M + m0;

  v2f basep = {0.f, 0.f};
  float omxA, osA, omxB, osB;

  if (flag) {
    basep = cb1 * x0p * x0p + cb3 * x1p * x1p + cb5 * x0p * x1p;
    v2f mx = {-INFINITY, -INFINITY};
    v2f s  = {0.f, 0.f};
    for (int m = 0; m < Mq; m += CHF) {
      v2f a[CHF];
#pragma unroll
      for (int j = 0; j < CHF; ++j) {
        const float c0 = C0[m + j], c2 = C2[m + j], c4 = C4[m + j];
        v2f t = x0p * c2 + c0;     // v_pk_fma_f32
        a[j] = x1p * c4 + t;       // v_pk_fma_f32
      }
      // COMPLETE packed max tree over all CHF elements (4 chains x 8)
      v2f t0 = PKMAX(a[0], a[1]);
      v2f t1 = PKMAX(a[2], a[3]);
      v2f t2 = PKMAX(a[4], a[5]);
      v2f t3 = PKMAX(a[6], a[7]);
#pragma unroll
      for (int j = 8; j < CHF; j += 4) {
        t0 = PKMAX(t0, a[j]);
        t1 = PKMAX(t1, a[j + 1]);
        t2 = PKMAX(t2, a[j + 2]);
        t3 = PKMAX(t3, a[j + 3]);
      }
      const v2f cm = PKMAX(PKMAX(t0, t1), PKMAX(t2, t3));
      const v2f nm = PKMAX(mx, cm);
      const v2f dm = mx - nm;              // <= 0; first chunk: -inf -> exp2 -> 0
      const v2f resc = {EXP2(dm.x), EXP2(dm.y)};
      v2f l0 = {0.f, 0.f}, l1 = {0.f, 0.f}, l2 = {0.f, 0.f}, l3 = {0.f, 0.f};
#pragma unroll
      for (int j = 0; j < CHF; j += 4) {
        const v2f d0 = a[j]     - nm;      // v_pk_add_f32
        const v2f d1 = a[j + 1] - nm;
        const v2f d2 = a[j + 2] - nm;
        const v2f d3 = a[j + 3] - nm;
        const v2f e0 = {EXP2(d0.x), EXP2(d0.y)};
        const v2f e1 = {EXP2(d1.x), EXP2(d1.y)};
        const v2f e2 = {EXP2(d2.x), EXP2(d2.y)};
        const v2f e3 = {EXP2(d3.x), EXP2(d3.y)};
        l0 += e0; l1 += e1; l2 += e2; l3 += e3;  // v_pk_add_f32
      }
      const v2f cs = (l0 + l1) + (l2 + l3);
      s = s * resc + cs;                   // v_pk_fma_f32
      mx = nm;
    }
    omxA = mx.x; osA = s.x; omxB = mx.y; osB = s.y;
  } else {
    float mxA = -INFINITY, sA = 0.0f;
    float mxB = -INFINITY, sB = 0.0f;
    for (int m = 0; m < Mq; m += CH) {
      v2f a[CH];
#pragma unroll
      for (int j = 0; j < CH; ++j) {
        const float c0 = C0[m + j], c1 = C1[m + j], c2 = C2[m + j];
        const float c3 = C3[m + j], c4 = C4[m + j], c5 = C5[m + j];
        v2f t0 = x0p * c1 + c2;
        t0 = x1p * c5 + t0;
        v2f t1 = x1p * c3 + c4;
        v2f r = t0 * x0p + c0;
        a[j] = t1 * x1p + r;
      }
      v2f cm01 = PKMAX(a[0], a[1]);
      v2f cm23 = PKMAX(a[2], a[3]);
      v2f cm45 = PKMAX(a[4], a[5]);
      v2f cm67 = PKMAX(a[6], a[7]);
#pragma unroll
      for (int j = 8; j < CH; j += 4) {
        cm01 = PKMAX(cm01, a[j]);
        cm23 = PKMAX(cm23, a[j + 1]);
        cm45 = PKMAX(cm45, a[j + 2]);
        cm67 = PKMAX(cm67, a[j + 3]);
      }
      const v2f cm = PKMAX(PKMAX(cm01, cm23), PKMAX(cm45, cm67));
      const float nmA = fmaxf(mxA, cm.x);
      const float nmB = fmaxf(mxB, cm.y);
      sA *= EXP2(mxA - nmA);
      sB *= EXP2(mxB - nmB);
      const v2f nmp = {nmA, nmB};
      float lA0 = 0.f, lA1 = 0.f, lB0 = 0.f, lB1 = 0.f;
#pragma unroll
      for (int j = 0; j < CH; j += 2) {
        const v2f d0 = a[j] - nmp;
        const v2f d1 = a[j + 1] - nmp;
        lA0 += EXP2(d0.x);
        lB0 += EXP2(d0.y);
        lA1 += EXP2(d1.x);
        lB1 += EXP2(d1.y);
      }
      sA += lA0 + lA1; mxA = nmA;
      sB += lB0 + lB1; mxB = nmB;
    }
    omxA = mxA; osA = sA; omxB = mxB; osB = sB;
  }

  // fold per-sample base into the partial max: logsumexp shifts uniformly
  Lmx[wave][0][lane] = omxA + basep.x; Lsm[wave][0][lane] = osA;
  Lmx[wave][1][lane] = omxB + basep.y; Lsm[wave][1][lane] = osB;
  __syncthreads();

  if (wave < 2) {
    const int set = wave;
    const int n = blockIdx.x * 128 + set * 64 + lane;
    if (n < N) {
      float gm = Lmx[0][set][lane];
#pragma unroll
      for (int v = 1; v < SPLIT; ++v) gm = fmaxf(gm, Lmx[v][set][lane]);
      float S = 0.f;
#pragma unroll
      for (int v = 0; v < SPLIT; ++v)
        S += Lsm[v][set][lane] * EXP2(Lmx[v][set][lane] - gm);
      out[n] = (gm + __log2f(S)) * 0.69314718055994530942f;
    }
  }
}

extern "C" void kernel_launch(void* const* d_in, const int* in_sizes, int n_in,
                              void* d_out, int out_size, void* d_ws, size_t ws_size,
                              hipStream_t stream) {
  const float* sample = (const float*)d_in[0];
  const float* mu     = (const float*)d_in[1];
  const float* A      = (const float*)d_in[2];
  const float* w      = (const float*)d_in[3];
  float* out = (float*)d_out;

  const int N = in_sizes[0] / 2;   // sample is (N,2)
  const int M = in_sizes[3];       // w is (M,1)

  float* C = (float*)d_ws;         // 6*M floats + 4-float header

  prep_kernel<<<1, 256, 0, stream>>>(mu, A, w, C, M);
  gmix_kernel<<<(N + 127) / 128, 512, 0, stream>>>(sample, C, out, N, M);
}